// Round 2
// baseline (263.956 us; speedup 1.0000x reference)
//
#include <hip/hip_runtime.h>

// ---------------------------------------------------------------------------
// Fused pre-LN MHA block on MI355X (gfx950).
// B=2, L=2048, D=768, H=12, Dh=64.  All matmuls via mfma_f32_16x16x32_bf16.
// Pipeline: LN -> (cvt weights) -> GEMM1 (qkv) -> flash-attn -> GEMM2+residual
// Workspace layout chosen at runtime from ws_size (T1 full / T2 per-batch /
// T3 per-batch + on-the-fly fp32 weight staging) so we NEVER write past d_ws.
// ---------------------------------------------------------------------------

#define DEV __device__ __forceinline__

typedef __attribute__((ext_vector_type(4))) float f32x4;
typedef __attribute__((ext_vector_type(8))) short s16x8;

constexpr int Bb   = 2;
constexpr int Ll   = 2048;
constexpr int Dd   = 768;
constexpr int Hh   = 12;
constexpr int Dh   = 64;
constexpr int Mrows = Bb * Ll;      // 4096
constexpr int N1   = 3 * Dd;        // 2304

DEV unsigned short f2bf(float f) {
  union { float f; unsigned u; } v; v.f = f;
  unsigned r = v.u + 0x7fffu + ((v.u >> 16) & 1u);
  return (unsigned short)(r >> 16);
}

DEV void gload_lds16(const void* g, void* l) {
  __builtin_amdgcn_global_load_lds((const __attribute__((address_space(1))) unsigned int*)g,
                                   (__attribute__((address_space(3))) unsigned int*)l,
                                   16, 0, 0);
}

DEV f32x4 mfma16(s16x8 a, s16x8 b, f32x4 c) {
  return __builtin_amdgcn_mfma_f32_16x16x32_bf16(a, b, c, 0, 0, 0);
}

// ---------------------------------------------------------------------------
// Kernel 1: LayerNorm fp32 -> bf16.  One block per row (768 elems, 256 thr).
// ---------------------------------------------------------------------------
__global__ __launch_bounds__(256) void ln_kernel(const float* __restrict__ x,
                                                 const float* __restrict__ gamma,
                                                 const float* __restrict__ beta,
                                                 short* __restrict__ hbuf) {
  const int row = blockIdx.x, t = threadIdx.x;
  const float* xr = x + (size_t)row * Dd;
  float v0 = xr[t], v1 = xr[t + 256], v2 = xr[t + 512];
  float s = v0 + v1 + v2;
  float q = v0 * v0 + v1 * v1 + v2 * v2;
#pragma unroll
  for (int off = 32; off; off >>= 1) {
    s += __shfl_xor(s, off, 64);
    q += __shfl_xor(q, off, 64);
  }
  __shared__ float red[8];
  const int w = t >> 6, lane = t & 63;
  if (lane == 0) { red[w] = s; red[4 + w] = q; }
  __syncthreads();
  s = red[0] + red[1] + red[2] + red[3];
  q = red[4] + red[5] + red[6] + red[7];
  const float mean = s * (1.f / Dd);
  const float var  = q * (1.f / Dd) - mean * mean;
  const float rstd = rsqrtf(var + 1e-5f);
  short* hr = hbuf + (size_t)row * Dd;
  hr[t]       = (short)f2bf((v0 - mean) * rstd * gamma[t]       + beta[t]);
  hr[t + 256] = (short)f2bf((v1 - mean) * rstd * gamma[t + 256] + beta[t + 256]);
  hr[t + 512] = (short)f2bf((v2 - mean) * rstd * gamma[t + 512] + beta[t + 512]);
}

// ---------------------------------------------------------------------------
// Kernel 2: convert w1 [2304*768] and w2 [768*768] fp32 -> bf16.
// ---------------------------------------------------------------------------
constexpr int W1E = N1 * Dd;     // 1769472
constexpr int W2E = Dd * Dd;     // 589824
__global__ __launch_bounds__(256) void cvt_kernel(const float* __restrict__ w1,
                                                  const float* __restrict__ w2,
                                                  short* __restrict__ w1b,
                                                  short* __restrict__ w2b) {
  int i = blockIdx.x * 256 + threadIdx.x;
  const int stride = gridDim.x * 256;
  for (; i < W1E + W2E; i += stride) {
    if (i < W1E) w1b[i] = (short)f2bf(w1[i]);
    else         w2b[i - W1E] = (short)f2bf(w2[i - W1E]);
  }
}

// ---------------------------------------------------------------------------
// GEMM (B^T form): C[m][n] = sum_k A[m][k] * W[n][k] (+bias)(+resid)
// 128x128 tile, BK=64, 4 waves (2x2), each wave 64x64 = 4x4 16x16 frags.
// EPI 0: bf16 store.  EPI 1: fp32 store + residual.
// WSRC 0: W is bf16, staged via global_load_lds.
// WSRC 1: W is fp32, staged via reg path with on-the-fly bf16 convert.
// ---------------------------------------------------------------------------
template <int EPI, int WSRC>
__global__ __launch_bounds__(256) void gemm_bt(const short* __restrict__ A,
                                               const void* __restrict__ Wp,
                                               const float* __restrict__ bias,
                                               const float* __restrict__ resid,
                                               void* __restrict__ outp,
                                               int N, int K) {
  __shared__ __align__(16) short As[128 * 64];
  __shared__ __align__(16) short Ws[128 * 64];
  const int tid  = threadIdx.x;
  const int lane = tid & 63, wid = tid >> 6;
  const int wr = wid >> 1, wc = wid & 1;
  const int g = lane >> 4, li = lane & 15;
  const int brow = blockIdx.y * 128, bcol = blockIdx.x * 128;

  f32x4 acc[4][4];
#pragma unroll
  for (int m = 0; m < 4; ++m)
#pragma unroll
    for (int n = 0; n < 4; ++n)
#pragma unroll
      for (int r = 0; r < 4; ++r) acc[m][n][r] = 0.f;

  for (int kt = 0; kt < K; kt += 64) {
#pragma unroll
    for (int i = 0; i < 4; ++i) {
      const int idx = i * 256 + tid;
      const int r = idx >> 3, c = idx & 7;
      gload_lds16(A + (size_t)(brow + r) * K + kt + c * 8, (char*)As + idx * 16);
    }
    if constexpr (WSRC == 0) {
      const short* W = (const short*)Wp;
#pragma unroll
      for (int i = 0; i < 4; ++i) {
        const int idx = i * 256 + tid;
        const int r = idx >> 3, c = idx & 7;
        gload_lds16(W + (size_t)(bcol + r) * K + kt + c * 8, (char*)Ws + idx * 16);
      }
    } else {
      const float* W = (const float*)Wp;
#pragma unroll
      for (int i = 0; i < 4; ++i) {
        const int idx = i * 256 + tid;
        const int r = idx >> 3, c = idx & 7;
        const float* wp = W + (size_t)(bcol + r) * K + kt + c * 8;
        const f32x4 lo = *(const f32x4*)wp;
        const f32x4 hi = *(const f32x4*)(wp + 4);
        s16x8 o;
#pragma unroll
        for (int j = 0; j < 4; ++j) {
          o[j]     = (short)f2bf(lo[j]);
          o[4 + j] = (short)f2bf(hi[j]);
        }
        *(s16x8*)((char*)Ws + idx * 16) = o;
      }
    }
    __syncthreads();
#pragma unroll
    for (int kk = 0; kk < 2; ++kk) {
      s16x8 af[4], bf[4];
#pragma unroll
      for (int m = 0; m < 4; ++m)
        af[m] = *(const s16x8*)&As[(wr * 64 + m * 16 + li) * 64 + kk * 32 + g * 8];
#pragma unroll
      for (int n = 0; n < 4; ++n)
        bf[n] = *(const s16x8*)&Ws[(wc * 64 + n * 16 + li) * 64 + kk * 32 + g * 8];
#pragma unroll
      for (int m = 0; m < 4; ++m)
#pragma unroll
        for (int n = 0; n < 4; ++n)
          acc[m][n] = mfma16(af[m], bf[n], acc[m][n]);
    }
    __syncthreads();
  }

#pragma unroll
  for (int m = 0; m < 4; ++m) {
#pragma unroll
    for (int n = 0; n < 4; ++n) {
      const int col = bcol + wc * 64 + n * 16 + li;
      const float bv = bias[col];
#pragma unroll
      for (int r = 0; r < 4; ++r) {
        const int row = brow + wr * 64 + m * 16 + g * 4 + r;
        const float v = acc[m][n][r] + bv;
        if (EPI == 0) {
          ((short*)outp)[(size_t)row * N + col] = (short)f2bf(v);
        } else {
          const size_t o = (size_t)row * N + col;
          ((float*)outp)[o] = v + resid[o];
        }
      }
    }
  }
}

// ---------------------------------------------------------------------------
// Flash attention.  Grid (L/128, nbatch*H).  4 waves; wave handles 32 Q rows.
// qkv layout: [nbatch*L][2304] bf16, q at +0, k at +768, v at +1536
// Out: obuf [nbatch*L][768] bf16 (col = h*64 + dh).
// ---------------------------------------------------------------------------
__global__ __launch_bounds__(256) void attn_kernel(const short* __restrict__ qkv,
                                                   short* __restrict__ obuf) {
  __shared__ __align__(16) short Ks[64 * 64];      // [kvrow][dh]
  __shared__ __align__(16) short Vts[64 * 64];     // [dh][kvrow] (transposed)
  __shared__ __align__(16) short Ps[4][32 * 64];   // per-wave P tile
  const int tid  = threadIdx.x;
  const int lane = tid & 63, w = tid >> 6;
  const int g = lane >> 4, li = lane & 15;
  const int bh = blockIdx.y;
  const int b = bh / Hh, h = bh % Hh;
  const size_t rowbase = (size_t)b * Ll * N1;
  const int q0 = blockIdx.x * 128 + w * 32;

  // Q fragments, kept in registers for the whole block
  s16x8 qf[2][2];
#pragma unroll
  for (int m = 0; m < 2; ++m)
#pragma unroll
    for (int ks = 0; ks < 2; ++ks)
      qf[m][ks] = *(const s16x8*)(qkv + rowbase + (size_t)(q0 + m * 16 + li) * N1 +
                                  h * Dh + ks * 32 + g * 8);

  f32x4 oa[2][4];
  float mr[2][4], lr[2][4];
#pragma unroll
  for (int m = 0; m < 2; ++m)
#pragma unroll
    for (int r = 0; r < 4; ++r) {
      mr[m][r] = -1e30f;
      lr[m][r] = 0.f;
#pragma unroll
      for (int dn = 0; dn < 4; ++dn) oa[m][dn][r] = 0.f;
    }

  for (int kt = 0; kt < Ll / 64; ++kt) {
    const size_t kbase = rowbase + (size_t)kt * 64 * N1;
    // stage K tile [64][64] linear via global_load_lds
#pragma unroll
    for (int i = 0; i < 2; ++i) {
      const int idx = i * 256 + tid;
      const int r = idx >> 3, c = idx & 7;
      gload_lds16(qkv + kbase + (size_t)r * N1 + Dd + h * Dh + c * 8,
                  (char*)Ks + idx * 16);
    }
    // stage V transposed (reg path): Vts[dh][kvrow]
#pragma unroll
    for (int i = 0; i < 2; ++i) {
      const int idx = i * 256 + tid;
      const int r = idx >> 3, c = idx & 7;
      s16x8 v = *(const s16x8*)(qkv + kbase + (size_t)r * N1 + 2 * Dd + h * Dh + c * 8);
#pragma unroll
      for (int j = 0; j < 8; ++j) Vts[(c * 8 + j) * 64 + r] = v[j];
    }
    __syncthreads();

    // S = Q K^T / 8
    s16x8 kf[4][2];
#pragma unroll
    for (int n = 0; n < 4; ++n)
#pragma unroll
      for (int ks = 0; ks < 2; ++ks)
        kf[n][ks] = *(const s16x8*)&Ks[(n * 16 + li) * 64 + ks * 32 + g * 8];

    f32x4 s[2][4];
#pragma unroll
    for (int m = 0; m < 2; ++m)
#pragma unroll
      for (int n = 0; n < 4; ++n) {
        f32x4 z;
#pragma unroll
        for (int r = 0; r < 4; ++r) z[r] = 0.f;
        z = mfma16(qf[m][0], kf[n][0], z);
        z = mfma16(qf[m][1], kf[n][1], z);
#pragma unroll
        for (int r = 0; r < 4; ++r) s[m][n][r] = z[r] * 0.125f;
      }

    // online softmax (row = m*16 + g*4 + r, col = n*16 + li)
#pragma unroll
    for (int m = 0; m < 2; ++m) {
#pragma unroll
      for (int r = 0; r < 4; ++r) {
        float mx = fmaxf(fmaxf(s[m][0][r], s[m][1][r]), fmaxf(s[m][2][r], s[m][3][r]));
#pragma unroll
        for (int off = 1; off < 16; off <<= 1) mx = fmaxf(mx, __shfl_xor(mx, off, 16));
        const float mnew = fmaxf(mr[m][r], mx);
        const float sc = __expf(mr[m][r] - mnew);
        float rs = 0.f;
#pragma unroll
        for (int n = 0; n < 4; ++n) {
          const float p = __expf(s[m][n][r] - mnew);
          s[m][n][r] = p;
          rs += p;
        }
#pragma unroll
        for (int off = 1; off < 16; off <<= 1) rs += __shfl_xor(rs, off, 16);
        lr[m][r] = lr[m][r] * sc + rs;
        mr[m][r] = mnew;
#pragma unroll
        for (int dn = 0; dn < 4; ++dn) oa[m][dn][r] *= sc;
      }
    }

    // P (C-layout) -> LDS -> A-fragment layout
    short* Pw = &Ps[w][0];
#pragma unroll
    for (int m = 0; m < 2; ++m)
#pragma unroll
      for (int n = 0; n < 4; ++n)
#pragma unroll
        for (int r = 0; r < 4; ++r)
          Pw[(m * 16 + g * 4 + r) * 64 + n * 16 + li] = (short)f2bf(s[m][n][r]);

    s16x8 pf[2][2], vf[4][2];
#pragma unroll
    for (int m = 0; m < 2; ++m)
#pragma unroll
      for (int kk = 0; kk < 2; ++kk)
        pf[m][kk] = *(const s16x8*)&Pw[(m * 16 + li) * 64 + kk * 32 + g * 8];
#pragma unroll
    for (int dn = 0; dn < 4; ++dn)
#pragma unroll
      for (int kk = 0; kk < 2; ++kk)
        vf[dn][kk] = *(const s16x8*)&Vts[(dn * 16 + li) * 64 + kk * 32 + g * 8];

#pragma unroll
    for (int m = 0; m < 2; ++m)
#pragma unroll
      for (int dn = 0; dn < 4; ++dn) {
        oa[m][dn] = mfma16(pf[m][0], vf[dn][0], oa[m][dn]);
        oa[m][dn] = mfma16(pf[m][1], vf[dn][1], oa[m][dn]);
      }
    __syncthreads();
  }

  // O / l -> bf16 obuf
#pragma unroll
  for (int m = 0; m < 2; ++m)
#pragma unroll
    for (int r = 0; r < 4; ++r) {
      const float inv = 1.f / lr[m][r];
      const int row = b * Ll + q0 + m * 16 + g * 4 + r;
#pragma unroll
      for (int dn = 0; dn < 4; ++dn)
        obuf[(size_t)row * Dd + h * Dh + dn * 16 + li] =
            (short)f2bf(oa[m][dn][r] * inv);
    }
}

// ---------------------------------------------------------------------------
extern "C" void kernel_launch(void* const* d_in, const int* in_sizes, int n_in,
                              void* d_out, int out_size, void* d_ws, size_t ws_size,
                              hipStream_t stream) {
  const float* x     = (const float*)d_in[0];
  const float* gamma = (const float*)d_in[1];
  const float* beta  = (const float*)d_in[2];
  const float* w1    = (const float*)d_in[3];
  const float* b1    = (const float*)d_in[4];
  const float* w2    = (const float*)d_in[5];
  const float* b2    = (const float*)d_in[6];
  float* out = (float*)d_out;
  char* ws = (char*)d_ws;

  if (ws_size >= 29884416) {
    // ---- T1: full batch in one pass.  ws = 29,884,416 B ----
    short* qkvb = (short*)(ws);              // 4096*2304*2 = 18874368
    short* hb   = (short*)(ws + 18874368);   // 4096*768*2  = 6291456 (hbuf, then obuf)
    short* w1b  = (short*)(ws + 25165824);   // 2304*768*2  = 3538944
    short* w2b  = (short*)(ws + 28704768);   // 768*768*2   = 1179648
    ln_kernel<<<dim3(Mrows), dim3(256), 0, stream>>>(x, gamma, beta, hb);
    cvt_kernel<<<dim3(1024), dim3(256), 0, stream>>>(w1, w2, w1b, w2b);
    gemm_bt<0, 0><<<dim3(N1 / 128, Mrows / 128), dim3(256), 0, stream>>>(
        hb, w1b, b1, nullptr, (void*)qkvb, N1, Dd);
    attn_kernel<<<dim3(Ll / 128, Bb * Hh), dim3(256), 0, stream>>>(qkvb, hb);
    gemm_bt<1, 0><<<dim3(Dd / 128, Mrows / 128), dim3(256), 0, stream>>>(
        hb, w2b, b2, x, (void*)out, Dd, Dd);
  } else if (ws_size >= 17301504) {
    // ---- T2: per-batch, bf16 weights.  ws = 17,301,504 B ----
    short* qkvb = (short*)(ws);              // 2048*2304*2 = 9437184
    short* hb   = (short*)(ws + 9437184);    // 2048*768*2  = 3145728 (hbuf/obuf)
    short* w1b  = (short*)(ws + 12582912);   // 3538944
    short* w2b  = (short*)(ws + 16121856);   // 1179648
    cvt_kernel<<<dim3(1024), dim3(256), 0, stream>>>(w1, w2, w1b, w2b);
    for (int b = 0; b < Bb; ++b) {
      const size_t ro = (size_t)b * Ll * Dd;
      ln_kernel<<<dim3(Ll), dim3(256), 0, stream>>>(x + ro, gamma, beta, hb);
      gemm_bt<0, 0><<<dim3(N1 / 128, Ll / 128), dim3(256), 0, stream>>>(
          hb, w1b, b1, nullptr, (void*)qkvb, N1, Dd);
      attn_kernel<<<dim3(Ll / 128, Hh), dim3(256), 0, stream>>>(qkvb, hb);
      gemm_bt<1, 0><<<dim3(Dd / 128, Ll / 128), dim3(256), 0, stream>>>(
          hb, w2b, b2, x + ro, (void*)(out + ro), Dd, Dd);
    }
  } else {
    // ---- T3: per-batch, fp32 weights staged on the fly.  ws = 12,582,912 B ----
    short* qkvb = (short*)(ws);              // 9437184
    short* hb   = (short*)(ws + 9437184);    // 3145728 (hbuf/obuf)
    for (int b = 0; b < Bb; ++b) {
      const size_t ro = (size_t)b * Ll * Dd;
      ln_kernel<<<dim3(Ll), dim3(256), 0, stream>>>(x + ro, gamma, beta, hb);
      gemm_bt<0, 1><<<dim3(N1 / 128, Ll / 128), dim3(256), 0, stream>>>(
          hb, w1, b1, nullptr, (void*)qkvb, N1, Dd);
      attn_kernel<<<dim3(Ll / 128, Hh), dim3(256), 0, stream>>>(qkvb, hb);
      gemm_bt<1, 1><<<dim3(Dd / 128, Ll / 128), dim3(256), 0, stream>>>(
          hb, w2, b2, x + ro, (void*)(out + ro), Dd, Dd);
    }
  }
}

// Round 3
// 167.547 us; speedup vs baseline: 1.5754x; 1.5754x over previous
//
#include <hip/hip_runtime.h>

// ---------------------------------------------------------------------------
// Fused pre-LN MHA block on MI355X (gfx950).
// B=2, L=2048, D=768, H=12, Dh=64.  All matmuls via mfma_f32_16x16x32_bf16.
// Pipeline: LN -> (cvt weights) -> GEMM1 (qkv) -> flash-attn -> GEMM2+residual
// R2: attn rewritten — 16 q-rows/wave (768 blocks), XOR-swizzled LDS (K, V^T,
// P all ~conflict-free), double-buffered K/V staging, one barrier/iter.
// GEMM LDS also swizzled via pre-swizzled global source (m173 pattern).
// ---------------------------------------------------------------------------

#define DEV __device__ __forceinline__

typedef __attribute__((ext_vector_type(4))) float f32x4;
typedef __attribute__((ext_vector_type(8))) short s16x8;

constexpr int Bb   = 2;
constexpr int Ll   = 2048;
constexpr int Dd   = 768;
constexpr int Hh   = 12;
constexpr int Dh   = 64;
constexpr int Mrows = Bb * Ll;      // 4096
constexpr int N1   = 3 * Dd;        // 2304

DEV unsigned short f2bf(float f) {
  union { float f; unsigned u; } v; v.f = f;
  unsigned r = v.u + 0x7fffu + ((v.u >> 16) & 1u);
  return (unsigned short)(r >> 16);
}

DEV void gload_lds16(const void* g, void* l) {
  __builtin_amdgcn_global_load_lds((const __attribute__((address_space(1))) unsigned int*)g,
                                   (__attribute__((address_space(3))) unsigned int*)l,
                                   16, 0, 0);
}

DEV f32x4 mfma16(s16x8 a, s16x8 b, f32x4 c) {
  return __builtin_amdgcn_mfma_f32_16x16x32_bf16(a, b, c, 0, 0, 0);
}

// ---------------------------------------------------------------------------
// Kernel 1: LayerNorm fp32 -> bf16.  One block per row (768 elems, 256 thr).
// ---------------------------------------------------------------------------
__global__ __launch_bounds__(256) void ln_kernel(const float* __restrict__ x,
                                                 const float* __restrict__ gamma,
                                                 const float* __restrict__ beta,
                                                 short* __restrict__ hbuf) {
  const int row = blockIdx.x, t = threadIdx.x;
  const float* xr = x + (size_t)row * Dd;
  float v0 = xr[t], v1 = xr[t + 256], v2 = xr[t + 512];
  float s = v0 + v1 + v2;
  float q = v0 * v0 + v1 * v1 + v2 * v2;
#pragma unroll
  for (int off = 32; off; off >>= 1) {
    s += __shfl_xor(s, off, 64);
    q += __shfl_xor(q, off, 64);
  }
  __shared__ float red[8];
  const int w = t >> 6, lane = t & 63;
  if (lane == 0) { red[w] = s; red[4 + w] = q; }
  __syncthreads();
  s = red[0] + red[1] + red[2] + red[3];
  q = red[4] + red[5] + red[6] + red[7];
  const float mean = s * (1.f / Dd);
  const float var  = q * (1.f / Dd) - mean * mean;
  const float rstd = rsqrtf(var + 1e-5f);
  short* hr = hbuf + (size_t)row * Dd;
  hr[t]       = (short)f2bf((v0 - mean) * rstd * gamma[t]       + beta[t]);
  hr[t + 256] = (short)f2bf((v1 - mean) * rstd * gamma[t + 256] + beta[t + 256]);
  hr[t + 512] = (short)f2bf((v2 - mean) * rstd * gamma[t + 512] + beta[t + 512]);
}

// ---------------------------------------------------------------------------
// Kernel 2: convert w1 [2304*768] and w2 [768*768] fp32 -> bf16.
// ---------------------------------------------------------------------------
constexpr int W1E = N1 * Dd;     // 1769472
constexpr int W2E = Dd * Dd;     // 589824
__global__ __launch_bounds__(256) void cvt_kernel(const float* __restrict__ w1,
                                                  const float* __restrict__ w2,
                                                  short* __restrict__ w1b,
                                                  short* __restrict__ w2b) {
  int i = blockIdx.x * 256 + threadIdx.x;
  const int stride = gridDim.x * 256;
  for (; i < W1E + W2E; i += stride) {
    if (i < W1E) w1b[i] = (short)f2bf(w1[i]);
    else         w2b[i - W1E] = (short)f2bf(w2[i - W1E]);
  }
}

// ---------------------------------------------------------------------------
// GEMM (B^T form): C[m][n] = sum_k A[m][k] * W[n][k] (+bias)(+resid)
// 128x128 tile, BK=64, 4 waves (2x2), each wave 64x64 = 4x4 16x16 frags.
// LDS tiles XOR-swizzled: logical (row, kblk) lives at LDS block
// row*8 + (kblk ^ (row&7)).  Staged via pre-swizzled GLOBAL source so the
// linear global_load_lds dest lands swizzled (m173).  Reads add the XOR.
// EPI 0: bf16 store.  EPI 1: fp32 store + residual.
// WSRC 0: W bf16 via global_load_lds.  WSRC 1: W fp32, reg-path cvt staging.
// ---------------------------------------------------------------------------
template <int EPI, int WSRC>
__global__ __launch_bounds__(256) void gemm_bt(const short* __restrict__ A,
                                               const void* __restrict__ Wp,
                                               const float* __restrict__ bias,
                                               const float* __restrict__ resid,
                                               void* __restrict__ outp,
                                               int N, int K) {
  __shared__ __align__(16) short As[128 * 64];
  __shared__ __align__(16) short Ws[128 * 64];
  const int tid  = threadIdx.x;
  const int lane = tid & 63, wid = tid >> 6;
  const int wr = wid >> 1, wc = wid & 1;
  const int g = lane >> 4, li = lane & 15;
  const int brow = blockIdx.y * 128, bcol = blockIdx.x * 128;

  f32x4 acc[4][4];
#pragma unroll
  for (int m = 0; m < 4; ++m)
#pragma unroll
    for (int n = 0; n < 4; ++n)
#pragma unroll
      for (int r = 0; r < 4; ++r) acc[m][n][r] = 0.f;

  for (int kt = 0; kt < K; kt += 64) {
#pragma unroll
    for (int i = 0; i < 4; ++i) {
      const int idx = i * 256 + tid;
      const int r = idx >> 3, c = idx & 7;
      const int cs = c ^ (r & 7);              // pre-swizzled source block
      gload_lds16(A + (size_t)(brow + r) * K + kt + cs * 8, (char*)As + idx * 16);
    }
    if constexpr (WSRC == 0) {
      const short* W = (const short*)Wp;
#pragma unroll
      for (int i = 0; i < 4; ++i) {
        const int idx = i * 256 + tid;
        const int r = idx >> 3, c = idx & 7;
        const int cs = c ^ (r & 7);
        gload_lds16(W + (size_t)(bcol + r) * K + kt + cs * 8, (char*)Ws + idx * 16);
      }
    } else {
      const float* W = (const float*)Wp;
#pragma unroll
      for (int i = 0; i < 4; ++i) {
        const int idx = i * 256 + tid;
        const int r = idx >> 3, c = idx & 7;
        const float* wp = W + (size_t)(bcol + r) * K + kt + c * 8;
        const f32x4 lo = *(const f32x4*)wp;
        const f32x4 hi = *(const f32x4*)(wp + 4);
        s16x8 o;
#pragma unroll
        for (int j = 0; j < 4; ++j) {
          o[j]     = (short)f2bf(lo[j]);
          o[4 + j] = (short)f2bf(hi[j]);
        }
        *(s16x8*)((char*)Ws + (size_t)(r * 8 + (c ^ (r & 7))) * 16) = o;  // swizzled dest
      }
    }
    __syncthreads();
#pragma unroll
    for (int kk = 0; kk < 2; ++kk) {
      s16x8 af[4], bf[4];
#pragma unroll
      for (int m = 0; m < 4; ++m) {
        const int row = wr * 64 + m * 16 + li;
        af[m] = *(const s16x8*)&As[row * 64 + (((kk * 4 + g) ^ (li & 7)) & 7) * 8];
      }
#pragma unroll
      for (int n = 0; n < 4; ++n) {
        const int row = wc * 64 + n * 16 + li;
        bf[n] = *(const s16x8*)&Ws[row * 64 + (((kk * 4 + g) ^ (li & 7)) & 7) * 8];
      }
#pragma unroll
      for (int m = 0; m < 4; ++m)
#pragma unroll
        for (int n = 0; n < 4; ++n)
          acc[m][n] = mfma16(af[m], bf[n], acc[m][n]);
    }
    __syncthreads();
  }

#pragma unroll
  for (int m = 0; m < 4; ++m) {
#pragma unroll
    for (int n = 0; n < 4; ++n) {
      const int col = bcol + wc * 64 + n * 16 + li;
      const float bv = bias[col];
#pragma unroll
      for (int r = 0; r < 4; ++r) {
        const int row = brow + wr * 64 + m * 16 + g * 4 + r;
        const float v = acc[m][n][r] + bv;
        if (EPI == 0) {
          ((short*)outp)[(size_t)row * N + col] = (short)f2bf(v);
        } else {
          const size_t o = (size_t)row * N + col;
          ((float*)outp)[o] = v + resid[o];
        }
      }
    }
  }
}

// ---------------------------------------------------------------------------
// Flash attention.  Grid (L/64, nbatch*H).  4 waves; wave handles 16 Q rows.
// KVBLK=64, double-buffered K and V^T tiles, one barrier per KV tile.
// LDS swizzles (all reads/writes <=2-way bank aliasing = free):
//   K  : logical (kvrow, kblk) at block kvrow*8 + (kblk ^ (kvrow&7)); staged
//        linearly by global_load_lds from pre-swizzled global source.
//   V^T: element (d, kv) at short offset d*64 + (((kv>>3)^(d>>3)^(d&7))&7)*8
//        + (kv&7)  — transpose writes AND b128 reads conflict-free.
//   P  : element (qr, kv) at qr*64 + (((kv>>3)^(qr&7))&7)*8 + (kv&7).
// ---------------------------------------------------------------------------
__global__ __launch_bounds__(256) void attn_kernel(const short* __restrict__ qkv,
                                                   short* __restrict__ obuf) {
  __shared__ __align__(16) short Ks[2][64 * 64];
  __shared__ __align__(16) short Vt[2][64 * 64];
  __shared__ __align__(16) short Ps[4][16 * 64];
  const int tid  = threadIdx.x;
  const int lane = tid & 63, w = tid >> 6;
  const int g = lane >> 4, li = lane & 15;
  const int bh = blockIdx.y;
  const int b = bh / Hh, h = bh % Hh;
  const size_t rowbase = (size_t)b * Ll * N1;
  const int q0 = blockIdx.x * 64 + w * 16;

  // Q fragments (A-operand): lane (g,li) holds Q[q0+li][ks*32+g*8 .. +7]
  s16x8 qf[2];
#pragma unroll
  for (int ks = 0; ks < 2; ++ks)
    qf[ks] = *(const s16x8*)(qkv + rowbase + (size_t)(q0 + li) * N1 +
                             h * Dh + ks * 32 + g * 8);

  f32x4 oa[4];
  float mr[4], lr[4];
#pragma unroll
  for (int r = 0; r < 4; ++r) {
    mr[r] = -1e30f;
    lr[r] = 0.f;
#pragma unroll
    for (int dn = 0; dn < 4; ++dn) oa[dn][r] = 0.f;
  }

  // per-thread staging coords: 512 16B-blocks over 2 iterations of 256 thr
  // idx = i*256+tid ; r = idx>>3 (tile row) ; c = idx&7 (8-elem col block)
  constexpr int NT = Ll / 64;  // 32 tiles

  // ---- prologue: stage tile 0 into buffer 0 ----
  {
#pragma unroll
    for (int i = 0; i < 2; ++i) {
      const int idx = i * 256 + tid;
      const int r = idx >> 3, c = idx & 7;
      gload_lds16(qkv + rowbase + (size_t)r * N1 + Dd + h * Dh + (c ^ (r & 7)) * 8,
                  (char*)&Ks[0][0] + idx * 16);
    }
#pragma unroll
    for (int i = 0; i < 2; ++i) {
      const int idx = i * 256 + tid;
      const int r = idx >> 3, c = idx & 7;
      s16x8 v = *(const s16x8*)(qkv + rowbase + (size_t)r * N1 + 2 * Dd + h * Dh + c * 8);
#pragma unroll
      for (int j = 0; j < 8; ++j) {
        const int d = c * 8 + j;
        Vt[0][d * 64 + ((((r >> 3) ^ c ^ j)) & 7) * 8 + (r & 7)] = v[j];
      }
    }
  }
  __syncthreads();

  for (int kt = 0; kt < NT; ++kt) {
    const int cur = kt & 1;
    const bool more = (kt + 1 < NT);
    s16x8 vnext[2];
    if (more) {
      const size_t kb = rowbase + (size_t)(kt + 1) * 64 * N1;
#pragma unroll
      for (int i = 0; i < 2; ++i) {
        const int idx = i * 256 + tid;
        const int r = idx >> 3, c = idx & 7;
        vnext[i] = *(const s16x8*)(qkv + kb + (size_t)r * N1 + 2 * Dd + h * Dh + c * 8);
      }
#pragma unroll
      for (int i = 0; i < 2; ++i) {
        const int idx = i * 256 + tid;
        const int r = idx >> 3, c = idx & 7;
        gload_lds16(qkv + kb + (size_t)r * N1 + Dd + h * Dh + (c ^ (r & 7)) * 8,
                    (char*)&Ks[cur ^ 1][0] + idx * 16);
      }
    }

    // ---- S = Q K^T / 8 ----
    f32x4 s[4];
#pragma unroll
    for (int n = 0; n < 4; ++n) {
      const int row = n * 16 + li;
      s16x8 kf0 = *(const s16x8*)&Ks[cur][row * 64 + ((g ^ (li & 7)) & 7) * 8];
      s16x8 kf1 = *(const s16x8*)&Ks[cur][row * 64 + (((4 + g) ^ (li & 7)) & 7) * 8];
      f32x4 z;
#pragma unroll
      for (int r = 0; r < 4; ++r) z[r] = 0.f;
      z = mfma16(qf[0], kf0, z);
      z = mfma16(qf[1], kf1, z);
#pragma unroll
      for (int r = 0; r < 4; ++r) s[n][r] = z[r] * 0.125f;
    }

    // ---- online softmax (row qr = g*4+r, col = n*16+li) ----
#pragma unroll
    for (int r = 0; r < 4; ++r) {
      float mx = fmaxf(fmaxf(s[0][r], s[1][r]), fmaxf(s[2][r], s[3][r]));
#pragma unroll
      for (int off = 1; off < 16; off <<= 1) mx = fmaxf(mx, __shfl_xor(mx, off, 16));
      const float mnew = fmaxf(mr[r], mx);
      const float sc = __expf(mr[r] - mnew);
      float rs = 0.f;
#pragma unroll
      for (int n = 0; n < 4; ++n) {
        const float p = __expf(s[n][r] - mnew);
        s[n][r] = p;
        rs += p;
      }
#pragma unroll
      for (int off = 1; off < 16; off <<= 1) rs += __shfl_xor(rs, off, 16);
      lr[r] = lr[r] * sc + rs;
      mr[r] = mnew;
#pragma unroll
      for (int dn = 0; dn < 4; ++dn) oa[dn][r] *= sc;
    }

    // ---- P (C-layout) -> per-wave LDS (swizzled) -> A fragments ----
    short* Pw = &Ps[w][0];
#pragma unroll
    for (int n = 0; n < 4; ++n)
#pragma unroll
      for (int r = 0; r < 4; ++r) {
        const int qr = g * 4 + r;
        Pw[qr * 64 + (((n * 2 + (li >> 3)) ^ (qr & 7)) & 7) * 8 + (li & 7)] =
            (short)f2bf(s[n][r]);
      }

    s16x8 pf[2], vf[4][2];
#pragma unroll
    for (int kk = 0; kk < 2; ++kk)
      pf[kk] = *(const s16x8*)&Pw[li * 64 + (((kk * 4 + g) ^ (li & 7)) & 7) * 8];
#pragma unroll
    for (int dn = 0; dn < 4; ++dn) {
      const int d = dn * 16 + li;
      const int dm = ((dn * 2 + (li >> 3)) ^ (li & 7)) & 7;
#pragma unroll
      for (int kk = 0; kk < 2; ++kk)
        vf[dn][kk] = *(const s16x8*)&Vt[cur][d * 64 + (((kk * 4 + g) ^ dm) & 7) * 8];
    }

#pragma unroll
    for (int dn = 0; dn < 4; ++dn) {
      oa[dn] = mfma16(pf[0], vf[dn][0], oa[dn]);
      oa[dn] = mfma16(pf[1], vf[dn][1], oa[dn]);
    }

    // ---- write next V tile (loads have drained under compute) ----
    if (more) {
#pragma unroll
      for (int i = 0; i < 2; ++i) {
        const int idx = i * 256 + tid;
        const int r = idx >> 3, c = idx & 7;
#pragma unroll
        for (int j = 0; j < 8; ++j) {
          const int d = c * 8 + j;
          Vt[cur ^ 1][d * 64 + ((((r >> 3) ^ c ^ j)) & 7) * 8 + (r & 7)] = vnext[i][j];
        }
      }
    }
    __syncthreads();
  }

  // ---- O / l -> bf16 obuf ----
#pragma unroll
  for (int r = 0; r < 4; ++r) {
    const float inv = 1.f / lr[r];
    const int row = b * Ll + q0 + g * 4 + r;
#pragma unroll
    for (int dn = 0; dn < 4; ++dn)
      obuf[(size_t)row * Dd + h * Dh + dn * 16 + li] =
          (short)f2bf(oa[dn][r] * inv);
  }
}

// ---------------------------------------------------------------------------
extern "C" void kernel_launch(void* const* d_in, const int* in_sizes, int n_in,
                              void* d_out, int out_size, void* d_ws, size_t ws_size,
                              hipStream_t stream) {
  const float* x     = (const float*)d_in[0];
  const float* gamma = (const float*)d_in[1];
  const float* beta  = (const float*)d_in[2];
  const float* w1    = (const float*)d_in[3];
  const float* b1    = (const float*)d_in[4];
  const float* w2    = (const float*)d_in[5];
  const float* b2    = (const float*)d_in[6];
  float* out = (float*)d_out;
  char* ws = (char*)d_ws;

  if (ws_size >= 29884416) {
    // ---- T1: full batch in one pass.  ws = 29,884,416 B ----
    short* qkvb = (short*)(ws);              // 4096*2304*2 = 18874368
    short* hb   = (short*)(ws + 18874368);   // 4096*768*2  = 6291456 (hbuf, then obuf)
    short* w1b  = (short*)(ws + 25165824);   // 2304*768*2  = 3538944
    short* w2b  = (short*)(ws + 28704768);   // 768*768*2   = 1179648
    ln_kernel<<<dim3(Mrows), dim3(256), 0, stream>>>(x, gamma, beta, hb);
    cvt_kernel<<<dim3(1024), dim3(256), 0, stream>>>(w1, w2, w1b, w2b);
    gemm_bt<0, 0><<<dim3(N1 / 128, Mrows / 128), dim3(256), 0, stream>>>(
        hb, w1b, b1, nullptr, (void*)qkvb, N1, Dd);
    attn_kernel<<<dim3(Ll / 64, Bb * Hh), dim3(256), 0, stream>>>(qkvb, hb);
    gemm_bt<1, 0><<<dim3(Dd / 128, Mrows / 128), dim3(256), 0, stream>>>(
        hb, w2b, b2, x, (void*)out, Dd, Dd);
  } else if (ws_size >= 17301504) {
    // ---- T2: per-batch, bf16 weights.  ws = 17,301,504 B ----
    short* qkvb = (short*)(ws);              // 2048*2304*2 = 9437184
    short* hb   = (short*)(ws + 9437184);    // 2048*768*2  = 3145728 (hbuf/obuf)
    short* w1b  = (short*)(ws + 12582912);   // 3538944
    short* w2b  = (short*)(ws + 16121856);   // 1179648
    cvt_kernel<<<dim3(1024), dim3(256), 0, stream>>>(w1, w2, w1b, w2b);
    for (int b = 0; b < Bb; ++b) {
      const size_t ro = (size_t)b * Ll * Dd;
      ln_kernel<<<dim3(Ll), dim3(256), 0, stream>>>(x + ro, gamma, beta, hb);
      gemm_bt<0, 0><<<dim3(N1 / 128, Ll / 128), dim3(256), 0, stream>>>(
          hb, w1b, b1, nullptr, (void*)qkvb, N1, Dd);
      attn_kernel<<<dim3(Ll / 64, Hh), dim3(256), 0, stream>>>(qkvb, hb);
      gemm_bt<1, 0><<<dim3(Dd / 128, Ll / 128), dim3(256), 0, stream>>>(
          hb, w2b, b2, x + ro, (void*)(out + ro), Dd, Dd);
    }
  } else {
    // ---- T3: per-batch, fp32 weights staged on the fly.  ws = 12,582,912 B ----
    short* qkvb = (short*)(ws);              // 9437184
    short* hb   = (short*)(ws + 9437184);    // 3145728 (hbuf/obuf)
    for (int b = 0; b < Bb; ++b) {
      const size_t ro = (size_t)b * Ll * Dd;
      ln_kernel<<<dim3(Ll), dim3(256), 0, stream>>>(x + ro, gamma, beta, hb);
      gemm_bt<0, 1><<<dim3(N1 / 128, Ll / 128), dim3(256), 0, stream>>>(
          hb, w1, b1, nullptr, (void*)qkvb, N1, Dd);
      attn_kernel<<<dim3(Ll / 64, Hh), dim3(256), 0, stream>>>(qkvb, hb);
      gemm_bt<1, 1><<<dim3(Dd / 128, Ll / 128), dim3(256), 0, stream>>>(
          hb, w2, b2, x + ro, (void*)(out + ro), Dd, Dd);
    }
  }
}

// Round 5
// 144.037 us; speedup vs baseline: 1.8326x; 1.1632x over previous
//
#include <hip/hip_runtime.h>

// ---------------------------------------------------------------------------
// Fused pre-LN MHA block on MI355X (gfx950).
// B=2, L=2048, D=768, H=12, Dh=64.  All matmuls via mfma_f32_16x16x32_bf16.
// Pipeline: LN -> (cvt weights) -> GEMM1 (qkv) -> flash-attn -> GEMM2+residual
// R4: fix ds_read_b64_tr_b16 addressing — it is a PER-LANE gather (4 bf16 at
// vaddr + j*32B); lane must supply vaddr = base + (l>>4)*256 + (l&15)*2.
// V LDS layout: subtile T holds V[kv=(T&15)*4+j][d=(T>>4)*16+c] at
// lds_bf16[T*64 + j*16 + c]; staged linear-dest via global_load_lds.
// ---------------------------------------------------------------------------

#define DEV __device__ __forceinline__

typedef __attribute__((ext_vector_type(4))) float f32x4;
typedef __attribute__((ext_vector_type(8))) short s16x8;
typedef __attribute__((ext_vector_type(2))) int i32x2;

constexpr int Bb   = 2;
constexpr int Ll   = 2048;
constexpr int Dd   = 768;
constexpr int Hh   = 12;
constexpr int Dh   = 64;
constexpr int Mrows = Bb * Ll;      // 4096
constexpr int N1   = 3 * Dd;        // 2304

DEV unsigned short f2bf(float f) {
  union { float f; unsigned u; } v; v.f = f;
  unsigned r = v.u + 0x7fffu + ((v.u >> 16) & 1u);
  return (unsigned short)(r >> 16);
}

DEV void gload_lds16(const void* g, void* l) {
  __builtin_amdgcn_global_load_lds((const __attribute__((address_space(1))) unsigned int*)g,
                                   (__attribute__((address_space(3))) unsigned int*)l,
                                   16, 0, 0);
}

DEV f32x4 mfma16(s16x8 a, s16x8 b, f32x4 c) {
  return __builtin_amdgcn_mfma_f32_16x16x32_bf16(a, b, c, 0, 0, 0);
}

// ---------------------------------------------------------------------------
// Kernel 1: LayerNorm fp32 -> bf16.  One block per row (768 elems, 256 thr).
// ---------------------------------------------------------------------------
__global__ __launch_bounds__(256) void ln_kernel(const float* __restrict__ x,
                                                 const float* __restrict__ gamma,
                                                 const float* __restrict__ beta,
                                                 short* __restrict__ hbuf) {
  const int row = blockIdx.x, t = threadIdx.x;
  const float* xr = x + (size_t)row * Dd;
  float v0 = xr[t], v1 = xr[t + 256], v2 = xr[t + 512];
  float s = v0 + v1 + v2;
  float q = v0 * v0 + v1 * v1 + v2 * v2;
#pragma unroll
  for (int off = 32; off; off >>= 1) {
    s += __shfl_xor(s, off, 64);
    q += __shfl_xor(q, off, 64);
  }
  __shared__ float red[8];
  const int w = t >> 6, lane = t & 63;
  if (lane == 0) { red[w] = s; red[4 + w] = q; }
  __syncthreads();
  s = red[0] + red[1] + red[2] + red[3];
  q = red[4] + red[5] + red[6] + red[7];
  const float mean = s * (1.f / Dd);
  const float var  = q * (1.f / Dd) - mean * mean;
  const float rstd = rsqrtf(var + 1e-5f);
  short* hr = hbuf + (size_t)row * Dd;
  hr[t]       = (short)f2bf((v0 - mean) * rstd * gamma[t]       + beta[t]);
  hr[t + 256] = (short)f2bf((v1 - mean) * rstd * gamma[t + 256] + beta[t + 256]);
  hr[t + 512] = (short)f2bf((v2 - mean) * rstd * gamma[t + 512] + beta[t + 512]);
}

// ---------------------------------------------------------------------------
// Kernel 2: convert w1 [2304*768] and w2 [768*768] fp32 -> bf16.
// ---------------------------------------------------------------------------
constexpr int W1E = N1 * Dd;     // 1769472
constexpr int W2E = Dd * Dd;     // 589824
__global__ __launch_bounds__(256) void cvt_kernel(const float* __restrict__ w1,
                                                  const float* __restrict__ w2,
                                                  short* __restrict__ w1b,
                                                  short* __restrict__ w2b) {
  int i = blockIdx.x * 256 + threadIdx.x;
  const int stride = gridDim.x * 256;
  for (; i < W1E + W2E; i += stride) {
    if (i < W1E) w1b[i] = (short)f2bf(w1[i]);
    else         w2b[i - W1E] = (short)f2bf(w2[i - W1E]);
  }
}

// ---------------------------------------------------------------------------
// GEMM (B^T form): C[m][n] = sum_k A[m][k] * W[n][k] (+bias)(+resid)
// 128x128 tile, BK=64, 4 waves (2x2), each wave 64x64 = 4x4 16x16 frags.
// LDS tiles XOR-swizzled via pre-swizzled global source (m173 pattern).
// ---------------------------------------------------------------------------
template <int EPI, int WSRC>
__global__ __launch_bounds__(256) void gemm_bt(const short* __restrict__ A,
                                               const void* __restrict__ Wp,
                                               const float* __restrict__ bias,
                                               const float* __restrict__ resid,
                                               void* __restrict__ outp,
                                               int N, int K) {
  __shared__ __align__(16) short As[128 * 64];
  __shared__ __align__(16) short Ws[128 * 64];
  const int tid  = threadIdx.x;
  const int lane = tid & 63, wid = tid >> 6;
  const int wr = wid >> 1, wc = wid & 1;
  const int g = lane >> 4, li = lane & 15;
  const int brow = blockIdx.y * 128, bcol = blockIdx.x * 128;

  f32x4 acc[4][4];
#pragma unroll
  for (int m = 0; m < 4; ++m)
#pragma unroll
    for (int n = 0; n < 4; ++n)
#pragma unroll
      for (int r = 0; r < 4; ++r) acc[m][n][r] = 0.f;

  for (int kt = 0; kt < K; kt += 64) {
#pragma unroll
    for (int i = 0; i < 4; ++i) {
      const int idx = i * 256 + tid;
      const int r = idx >> 3, c = idx & 7;
      const int cs = c ^ (r & 7);              // pre-swizzled source block
      gload_lds16(A + (size_t)(brow + r) * K + kt + cs * 8, (char*)As + idx * 16);
    }
    if constexpr (WSRC == 0) {
      const short* W = (const short*)Wp;
#pragma unroll
      for (int i = 0; i < 4; ++i) {
        const int idx = i * 256 + tid;
        const int r = idx >> 3, c = idx & 7;
        const int cs = c ^ (r & 7);
        gload_lds16(W + (size_t)(bcol + r) * K + kt + cs * 8, (char*)Ws + idx * 16);
      }
    } else {
      const float* W = (const float*)Wp;
#pragma unroll
      for (int i = 0; i < 4; ++i) {
        const int idx = i * 256 + tid;
        const int r = idx >> 3, c = idx & 7;
        const float* wp = W + (size_t)(bcol + r) * K + kt + c * 8;
        const f32x4 lo = *(const f32x4*)wp;
        const f32x4 hi = *(const f32x4*)(wp + 4);
        s16x8 o;
#pragma unroll
        for (int j = 0; j < 4; ++j) {
          o[j]     = (short)f2bf(lo[j]);
          o[4 + j] = (short)f2bf(hi[j]);
        }
        *(s16x8*)((char*)Ws + (size_t)(r * 8 + (c ^ (r & 7))) * 16) = o;  // swizzled dest
      }
    }
    __syncthreads();
#pragma unroll
    for (int kk = 0; kk < 2; ++kk) {
      s16x8 af[4], bf[4];
#pragma unroll
      for (int m = 0; m < 4; ++m) {
        const int row = wr * 64 + m * 16 + li;
        af[m] = *(const s16x8*)&As[row * 64 + (((kk * 4 + g) ^ (li & 7)) & 7) * 8];
      }
#pragma unroll
      for (int n = 0; n < 4; ++n) {
        const int row = wc * 64 + n * 16 + li;
        bf[n] = *(const s16x8*)&Ws[row * 64 + (((kk * 4 + g) ^ (li & 7)) & 7) * 8];
      }
#pragma unroll
      for (int m = 0; m < 4; ++m)
#pragma unroll
        for (int n = 0; n < 4; ++n)
          acc[m][n] = mfma16(af[m], bf[n], acc[m][n]);
    }
    __syncthreads();
  }

#pragma unroll
  for (int m = 0; m < 4; ++m) {
#pragma unroll
    for (int n = 0; n < 4; ++n) {
      const int col = bcol + wc * 64 + n * 16 + li;
      const float bv = bias[col];
#pragma unroll
      for (int r = 0; r < 4; ++r) {
        const int row = brow + wr * 64 + m * 16 + g * 4 + r;
        const float v = acc[m][n][r] + bv;
        if (EPI == 0) {
          ((short*)outp)[(size_t)row * N + col] = (short)f2bf(v);
        } else {
          const size_t o = (size_t)row * N + col;
          ((float*)outp)[o] = v + resid[o];
        }
      }
    }
  }
}

// ---------------------------------------------------------------------------
// Flash attention R4.  Grid (L/64, nbatch*H).  4 waves; wave owns 16 Q rows.
// Swapped QK^T: S^T = mfma(K, Q) -> lane (g,li) holds S[kv=n*16+g*4+r][q=li];
// softmax per-lane scalar (q=li), cross-g via 2 shfl_xor (16,32).
// P: pack kv-quads -> 4 ds_write_b64 into swizzled Ps; read as A-frag (2 b128).
// V: global_load_lds into subtiled layout (see header); consumed by
// ds_read_b64_tr_b16 with PER-LANE addr base + (l>>4)*256 + (l&15)*2 and
// compile-time offsets dn*2048 + kk*1024 + half*128.
// K: XOR-swizzled via pre-swizzled global source.
// ---------------------------------------------------------------------------
#define TRRD(dst, addr, OFF)                                                   \
  asm volatile("ds_read_b64_tr_b16 %0, %1 offset:" #OFF                        \
               : "=v"(dst) : "v"(addr))

__global__ __launch_bounds__(256) void attn_kernel(const short* __restrict__ qkv,
                                                   short* __restrict__ obuf) {
  __shared__ __align__(16) short Ks[2][64 * 64];
  __shared__ __align__(16) short Vt[2][64 * 64];
  __shared__ __align__(16) short Ps[4][16 * 64];
  const int tid  = threadIdx.x;
  const int lane = tid & 63, w = tid >> 6;
  const int g = lane >> 4, li = lane & 15;
  const int bh = blockIdx.y;
  const int b = bh / Hh, h = bh % Hh;
  const size_t rowbase = (size_t)b * Ll * N1;
  const int q0 = blockIdx.x * 64 + w * 16;
  constexpr float kScale = 0.125f * 1.44269504f;  // 1/sqrt(Dh) * log2(e)

  // Q fragments (B operand of swapped QK^T; same lane map as A-frag)
  s16x8 qf[2];
#pragma unroll
  for (int ks = 0; ks < 2; ++ks)
    qf[ks] = *(const s16x8*)(qkv + rowbase + (size_t)(q0 + li) * N1 +
                             h * Dh + ks * 32 + g * 8);

  f32x4 oa[4];
  float m_ = -1e30f, l_ = 0.f;   // per-lane: q = li
#pragma unroll
  for (int dn = 0; dn < 4; ++dn)
#pragma unroll
    for (int r = 0; r < 4; ++r) oa[dn][r] = 0.f;

  constexpr int NT = Ll / 64;  // 32 tiles

  // ---- staging helpers (dest lane-linear; structure in SOURCE addr) ----
  auto stageK = [&](int t, int buf) {
    const size_t kb = rowbase + (size_t)t * 64 * N1 + Dd + h * Dh;
#pragma unroll
    for (int i = 0; i < 2; ++i) {
      const int idx = i * 256 + tid;
      const int r = idx >> 3, c = idx & 7;
      gload_lds16(qkv + kb + (size_t)r * N1 + (c ^ (r & 7)) * 8,
                  (char*)&Ks[buf][0] + idx * 16);
    }
  };
  auto stageV = [&](int t, int buf) {
    const size_t kb = rowbase + (size_t)t * 64 * N1 + 2 * Dd + h * Dh;
#pragma unroll
    for (int i = 0; i < 2; ++i) {
      const int idx = i * 256 + tid;
      const int T  = idx >> 3;
      const int kv = (T & 15) * 4 + ((idx & 7) >> 1);
      const int d0 = (T >> 4) * 16 + (idx & 1) * 8;
      gload_lds16(qkv + kb + (size_t)kv * N1 + d0, (char*)&Vt[buf][0] + idx * 16);
    }
  };

  stageK(0, 0);
  stageV(0, 0);
  __syncthreads();

  for (int kt = 0; kt < NT; ++kt) {
    const int cur = kt & 1;
    if (kt + 1 < NT) {
      stageK(kt + 1, cur ^ 1);
      stageV(kt + 1, cur ^ 1);
    }

    // ---- S^T = mfma(K, Q) * scale (exp2 domain) ----
    f32x4 s[4];
#pragma unroll
    for (int n = 0; n < 4; ++n) {
      const int row = n * 16 + li;
      s16x8 kf0 = *(const s16x8*)&Ks[cur][row * 64 + ((g ^ (li & 7)) & 7) * 8];
      s16x8 kf1 = *(const s16x8*)&Ks[cur][row * 64 + (((4 + g) ^ (li & 7)) & 7) * 8];
      f32x4 z;
#pragma unroll
      for (int r = 0; r < 4; ++r) z[r] = 0.f;
      z = mfma16(kf0, qf[0], z);
      z = mfma16(kf1, qf[1], z);
#pragma unroll
      for (int r = 0; r < 4; ++r) s[n][r] = z[r] * kScale;
    }

    // ---- online softmax, per-lane q-row ----
    float mx = fmaxf(fmaxf(fmaxf(s[0][0], s[0][1]), fmaxf(s[0][2], s[0][3])),
                     fmaxf(fmaxf(s[1][0], s[1][1]), fmaxf(s[1][2], s[1][3])));
    mx = fmaxf(mx, fmaxf(fmaxf(fmaxf(s[2][0], s[2][1]), fmaxf(s[2][2], s[2][3])),
                         fmaxf(fmaxf(s[3][0], s[3][1]), fmaxf(s[3][2], s[3][3]))));
    mx = fmaxf(mx, __shfl_xor(mx, 16, 64));
    mx = fmaxf(mx, __shfl_xor(mx, 32, 64));
    const float mnew = fmaxf(m_, mx);
    const float sc = exp2f(m_ - mnew);
    float rs = 0.f;
#pragma unroll
    for (int n = 0; n < 4; ++n)
#pragma unroll
      for (int r = 0; r < 4; ++r) {
        s[n][r] = exp2f(s[n][r] - mnew);
        rs += s[n][r];
      }
    rs += __shfl_xor(rs, 16, 64);
    rs += __shfl_xor(rs, 32, 64);
    l_ = l_ * sc + rs;
    m_ = mnew;

    // ---- rescale oa by sc of its q-row (q = g*4+r, from lane (g, q)) ----
    {
      const int sbase = (lane & 48) + ((lane & 48) >> 2);
      float scq[4];
#pragma unroll
      for (int r = 0; r < 4; ++r) scq[r] = __shfl(sc, sbase + r, 64);
#pragma unroll
      for (int dn = 0; dn < 4; ++dn)
#pragma unroll
        for (int r = 0; r < 4; ++r) oa[dn][r] *= scq[r];
    }

    // ---- P pack -> swizzled per-wave LDS (4 x ds_write_b64) ----
    {
      char* Pb = (char*)&Ps[w][0];
#pragma unroll
      for (int n = 0; n < 4; ++n) {
        const unsigned u0 = (unsigned)f2bf(s[n][0]) | ((unsigned)f2bf(s[n][1]) << 16);
        const unsigned u1 = (unsigned)f2bf(s[n][2]) | ((unsigned)f2bf(s[n][3]) << 16);
        i32x2 pv; pv[0] = (int)u0; pv[1] = (int)u1;
        const int off = li * 128 + (((2 * n + (g >> 1)) ^ (li & 7)) << 4) + 8 * (g & 1);
        *(i32x2*)(Pb + off) = pv;
      }
    }

    // ---- P A-frag reads (2 x b128) ----
    s16x8 pf[2];
#pragma unroll
    for (int kk = 0; kk < 2; ++kk)
      pf[kk] = *(const s16x8*)((char*)&Ps[w][0] + li * 128 +
                               (((4 * kk + g) ^ (li & 7)) << 4));

    // ---- V^T fragments via HW transpose reads (16 x ds_read_b64_tr_b16) ----
    // per-lane addr: base + (l>>4)*256 + (l&15)*2 ; offset dn*2048+kk*1024+half*128
    union VU { long l[2]; s16x8 v; };
    VU vu[4][2];
    {
      const unsigned vaddr = (unsigned)(unsigned long long)(&Vt[cur][0]) +
                             (unsigned)((lane >> 4) * 256 + (lane & 15) * 2);
      TRRD(vu[0][0].l[0], vaddr, 0);    TRRD(vu[0][0].l[1], vaddr, 128);
      TRRD(vu[0][1].l[0], vaddr, 1024); TRRD(vu[0][1].l[1], vaddr, 1152);
      TRRD(vu[1][0].l[0], vaddr, 2048); TRRD(vu[1][0].l[1], vaddr, 2176);
      TRRD(vu[1][1].l[0], vaddr, 3072); TRRD(vu[1][1].l[1], vaddr, 3200);
      TRRD(vu[2][0].l[0], vaddr, 4096); TRRD(vu[2][0].l[1], vaddr, 4224);
      TRRD(vu[2][1].l[0], vaddr, 5120); TRRD(vu[2][1].l[1], vaddr, 5248);
      TRRD(vu[3][0].l[0], vaddr, 6144); TRRD(vu[3][0].l[1], vaddr, 6272);
      TRRD(vu[3][1].l[0], vaddr, 7168); TRRD(vu[3][1].l[1], vaddr, 7296);
    }
    asm volatile("s_waitcnt lgkmcnt(0)" ::: "memory");
    __builtin_amdgcn_sched_barrier(0);

    // ---- O += P V ----
#pragma unroll
    for (int dn = 0; dn < 4; ++dn) {
      oa[dn] = mfma16(pf[0], vu[dn][0].v, oa[dn]);
      oa[dn] = mfma16(pf[1], vu[dn][1].v, oa[dn]);
    }
    __syncthreads();
  }

  // ---- O / l -> bf16 obuf (row q = q0 + g*4 + r) ----
  {
    const int sbase = (lane & 48) + ((lane & 48) >> 2);
#pragma unroll
    for (int r = 0; r < 4; ++r) {
      const float lq = __shfl(l_, sbase + r, 64);
      const float inv = 1.f / lq;
      const int row = b * Ll + q0 + g * 4 + r;
#pragma unroll
      for (int dn = 0; dn < 4; ++dn)
        obuf[(size_t)row * Dd + h * Dh + dn * 16 + li] =
            (short)f2bf(oa[dn][r] * inv);
    }
  }
}

// ---------------------------------------------------------------------------
extern "C" void kernel_launch(void* const* d_in, const int* in_sizes, int n_in,
                              void* d_out, int out_size, void* d_ws, size_t ws_size,
                              hipStream_t stream) {
  const float* x     = (const float*)d_in[0];
  const float* gamma = (const float*)d_in[1];
  const float* beta  = (const float*)d_in[2];
  const float* w1    = (const float*)d_in[3];
  const float* b1    = (const float*)d_in[4];
  const float* w2    = (const float*)d_in[5];
  const float* b2    = (const float*)d_in[6];
  float* out = (float*)d_out;
  char* ws = (char*)d_ws;

  if (ws_size >= 29884416) {
    // ---- T1: full batch in one pass.  ws = 29,884,416 B ----
    short* qkvb = (short*)(ws);              // 4096*2304*2 = 18874368
    short* hb   = (short*)(ws + 18874368);   // 4096*768*2  = 6291456 (hbuf, then obuf)
    short* w1b  = (short*)(ws + 25165824);   // 2304*768*2  = 3538944
    short* w2b  = (short*)(ws + 28704768);   // 768*768*2   = 1179648
    ln_kernel<<<dim3(Mrows), dim3(256), 0, stream>>>(x, gamma, beta, hb);
    cvt_kernel<<<dim3(1024), dim3(256), 0, stream>>>(w1, w2, w1b, w2b);
    gemm_bt<0, 0><<<dim3(N1 / 128, Mrows / 128), dim3(256), 0, stream>>>(
        hb, w1b, b1, nullptr, (void*)qkvb, N1, Dd);
    attn_kernel<<<dim3(Ll / 64, Bb * Hh), dim3(256), 0, stream>>>(qkvb, hb);
    gemm_bt<1, 0><<<dim3(Dd / 128, Mrows / 128), dim3(256), 0, stream>>>(
        hb, w2b, b2, x, (void*)out, Dd, Dd);
  } else if (ws_size >= 17301504) {
    // ---- T2: per-batch, bf16 weights.  ws = 17,301,504 B ----
    short* qkvb = (short*)(ws);              // 2048*2304*2 = 9437184
    short* hb   = (short*)(ws + 9437184);    // 2048*768*2  = 3145728 (hbuf/obuf)
    short* w1b  = (short*)(ws + 12582912);   // 3538944
    short* w2b  = (short*)(ws + 16121856);   // 1179648
    cvt_kernel<<<dim3(1024), dim3(256), 0, stream>>>(w1, w2, w1b, w2b);
    for (int b = 0; b < Bb; ++b) {
      const size_t ro = (size_t)b * Ll * Dd;
      ln_kernel<<<dim3(Ll), dim3(256), 0, stream>>>(x + ro, gamma, beta, hb);
      gemm_bt<0, 0><<<dim3(N1 / 128, Ll / 128), dim3(256), 0, stream>>>(
          hb, w1b, b1, nullptr, (void*)qkvb, N1, Dd);
      attn_kernel<<<dim3(Ll / 64, Hh), dim3(256), 0, stream>>>(qkvb, hb);
      gemm_bt<1, 0><<<dim3(Dd / 128, Ll / 128), dim3(256), 0, stream>>>(
          hb, w2b, b2, x + ro, (void*)(out + ro), Dd, Dd);
    }
  } else {
    // ---- T3: per-batch, fp32 weights staged on the fly.  ws = 12,582,912 B ----
    short* qkvb = (short*)(ws);              // 9437184
    short* hb   = (short*)(ws + 9437184);    // 3145728 (hbuf/obuf)
    for (int b = 0; b < Bb; ++b) {
      const size_t ro = (size_t)b * Ll * Dd;
      ln_kernel<<<dim3(Ll), dim3(256), 0, stream>>>(x + ro, gamma, beta, hb);
      gemm_bt<0, 1><<<dim3(N1 / 128, Ll / 128), dim3(256), 0, stream>>>(
          hb, w1, b1, nullptr, (void*)qkvb, N1, Dd);
      attn_kernel<<<dim3(Ll / 64, Hh), dim3(256), 0, stream>>>(qkvb, hb);
      gemm_bt<1, 1><<<dim3(Dd / 128, Ll / 128), dim3(256), 0, stream>>>(
          hb, w2, b2, x + ro, (void*)(out + ro), Dd, Dd);
    }
  }
}